// Round 14
// baseline (422.901 us; speedup 1.0000x reference)
//
#include <hip/hip_runtime.h>
#include <hip/hip_bf16.h>
#include <math.h>

#define NEG_SLOPE 0.2f
#define BN_EPS 1e-5f
#define LOG2E 1.44269504f

using frag  = __attribute__((ext_vector_type(8))) short;   // 8 x bf16
using f32x4 = __attribute__((ext_vector_type(4))) float;
using f32x2 = __attribute__((ext_vector_type(2))) float;   // -> v_pk_* ops

#define GLOAD_LDS16(gp, lp) __builtin_amdgcn_global_load_lds( \
    (const __attribute__((address_space(1))) void*)(gp),      \
    (__attribute__((address_space(3))) void*)(lp), 16, 0, 0)

// --- merged one-time work: y=0 x cast, y=1..6 W transposes, y=7 count_deg ---
__global__ __launch_bounds__(256) void conv_all(
        const float* __restrict__ x, __hip_bfloat16* __restrict__ xbf, int n4,
        const float* __restrict__ W1l, const float* __restrict__ W1r,
        const float* __restrict__ W2l, const float* __restrict__ W2r,
        const float* __restrict__ W3l, const float* __restrict__ W3r,
        __hip_bfloat16* __restrict__ Wc1, __hip_bfloat16* __restrict__ Wc2,
        __hip_bfloat16* __restrict__ Wc3, int INF, int HC, int OUTF,
        const int* __restrict__ ei, int E, int Etot, int* __restrict__ deg) {
    if (blockIdx.y == 0) {
        int i = blockIdx.x * 256 + threadIdx.x;
        if (i >= n4) return;
        float4 v = *(const float4*)(x + (size_t)i * 4);
        __hip_bfloat16 h[4] = {__float2bfloat16(v.x), __float2bfloat16(v.y),
                               __float2bfloat16(v.z), __float2bfloat16(v.w)};
        *(uint2*)(xbf + (size_t)i * 4) = *(const uint2*)h;
        return;
    }
    if (blockIdx.y == 7) {                    // count_deg slice
        int e = blockIdx.x * 256 + threadIdx.x;
        if (e >= Etot) return;
        int d = (e < E) ? ei[E + e] : (e - E);   // self-loop for e >= E
        atomicAdd(&deg[d], 1);
        return;
    }
    const float* W; __hip_bfloat16* Wt; int K, Nn;
    switch (blockIdx.y) {
        case 1:  W = W1l; Wt = Wc1;              K = INF; Nn = HC;   break;
        case 2:  W = W1r; Wt = Wc1 + HC * INF;   K = INF; Nn = HC;   break;
        case 3:  W = W2l; Wt = Wc2;              K = HC;  Nn = HC;   break;
        case 4:  W = W2r; Wt = Wc2 + HC * HC;    K = HC;  Nn = HC;   break;
        case 5:  W = W3l; Wt = Wc3;              K = HC;  Nn = OUTF; break;
        default: W = W3r; Wt = Wc3 + OUTF * HC;  K = HC;  Nn = OUTF; break;
    }
    int i = blockIdx.x * 256 + threadIdx.x;
    if (i >= K * Nn) return;
    int k = i / Nn, n = i - k * Nn;
    Wt[n * K + k] = __float2bfloat16(W[i]);
}

// --------- bf16 MFMA GEMM: C[M,NC](bf16) = A[M,K](bf16) @ Bt[NC,K]^T ---------
// 128x128 tile, BK=32, 256 threads (4 waves 2x2), dbuf LDS via global_load_lds,
// XOR swizzle on both sides; epilogue staged through LDS for coalesced stores.
template <int K>
__global__ __launch_bounds__(256) void gemm_mfma(
        const __hip_bfloat16* __restrict__ A,
        const __hip_bfloat16* __restrict__ Bt,
        __hip_bfloat16* __restrict__ C,
        int M, int NC) {
    constexpr int KS = K / 32;
    // overlay: staging (2*[128][32] x2 = 32 KB) then C-tile [128][144] (36.9 KB)
    __shared__ __align__(16) __hip_bfloat16 smem[128 * 144];
    auto Alds = reinterpret_cast<__hip_bfloat16(*)[128][32]>(smem);          // [2][128][32]
    auto Blds = reinterpret_cast<__hip_bfloat16(*)[128][32]>(smem + 8192);   // [2][128][32]
    const int tid  = threadIdx.x;
    const int w    = tid >> 6;
    const int lane = tid & 63;
    const int wr   = w >> 1, wc = w & 1;
    const int bm = blockIdx.y * 128, bn = blockIdx.x * 128;

    auto stage = [&](int t, int b) {
        const int k0 = t * 32;
#pragma unroll
        for (int i = 0; i < 2; ++i) {
            int ld    = (w << 1) | i;          // 0..7
            int rrel0 = ld << 4;               // 16-row group
            int rrel  = rrel0 + (lane >> 2);
            int slot  = lane & 3;
            int cg    = ((slot ^ ((rrel >> 1) & 3)) << 3);  // pre-swizzled col grp
            int arow  = bm + rrel; arow = arow < M ? arow : M - 1;
            GLOAD_LDS16(A  + (size_t)arow * K + k0 + cg, &Alds[b][rrel0][0]);
            int brow  = bn + rrel;             // NC multiple of 128 -> in range
            GLOAD_LDS16(Bt + (size_t)brow * K + k0 + cg, &Blds[b][rrel0][0]);
        }
    };

    f32x4 acc[4][4] = {};
    stage(0, 0);
    __syncthreads();                           // drains vmcnt before reads

    const int fr = lane & 15, fq = lane >> 4;
    for (int t = 0; t < KS; ++t) {
        const int b = t & 1;
        if (t + 1 < KS) stage(t + 1, b ^ 1);
        frag af[4], bf[4];
#pragma unroll
        for (int mf = 0; mf < 4; ++mf) {
            int arel = (wr << 6) + (mf << 4) + fr;
            int p = fq ^ ((arel >> 1) & 3);
            af[mf] = *(const frag*)&Alds[b][arel][p << 3];
        }
#pragma unroll
        for (int nf = 0; nf < 4; ++nf) {
            int nrel = (wc << 6) + (nf << 4) + fr;
            int p = fq ^ ((nrel >> 1) & 3);
            bf[nf] = *(const frag*)&Blds[b][nrel][p << 3];
        }
#pragma unroll
        for (int mf = 0; mf < 4; ++mf)
#pragma unroll
            for (int nf = 0; nf < 4; ++nf)
                acc[mf][nf] = __builtin_amdgcn_mfma_f32_16x16x32_bf16(
                    af[mf], bf[nf], acc[mf][nf], 0, 0, 0);
        __syncthreads();                       // also drains next-stage vmcnt
    }

    // ---- epilogue: fragments -> LDS -> coalesced 16B/lane stores ----
    // C/D layout: col = lane&15, row = (lane>>4)*4 + reg   [m89-verified]
    auto Cs = reinterpret_cast<__hip_bfloat16(*)[144]>(smem);  // stride 288B
#pragma unroll
    for (int mf = 0; mf < 4; ++mf)
#pragma unroll
        for (int nf = 0; nf < 4; ++nf)
#pragma unroll
            for (int r = 0; r < 4; ++r)
                Cs[(wr << 6) + (mf << 4) + (fq << 2) + r]
                  [(wc << 6) + (nf << 4) + fr] = __float2bfloat16(acc[mf][nf][r]);
    __syncthreads();
    const int rrow  = tid >> 4;                // 0..15
    const int chunk = tid & 15;                // 16B chunk within row
#pragma unroll
    for (int pass = 0; pass < 8; ++pass) {
        int lr = pass * 16 + rrow;
        int grow = bm + lr;
        if (grow < M) {
            uint4 v = *(const uint4*)&Cs[lr][chunk << 3];
            *(uint4*)(C + (size_t)grow * NC + bn + (chunk << 3)) = v;
        }
    }
}

// scan of PADDED degrees + per-block degree histogram (fused)
__global__ __launch_bounds__(1024) void scan1h(const int* __restrict__ deg,
                                               int* __restrict__ pre,
                                               int* __restrict__ bsum,
                                               int* __restrict__ bcnt,
                                               int n, int nblk) {
    __shared__ int buf[1024];
    __shared__ int lh[64];
    int t = threadIdx.x;
    if (t < 64) lh[t] = 0;
    __syncthreads();
    int i = blockIdx.x * 1024 + t;
    int d = (i < n) ? deg[i] : 0;
    if (i < n) atomicAdd(&lh[64 - min(d, 64)], 1);
    int v = (i < n) ? ((d + 3) & ~3) : 0;    // padded degree
    buf[t] = v;
    __syncthreads();
#pragma unroll
    for (int off = 1; off < 1024; off <<= 1) {
        int xv = (t >= off) ? buf[t - off] : 0;
        __syncthreads();
        buf[t] += xv;
        __syncthreads();
    }
    if (i < n) pre[i] = buf[t] - v;          // exclusive within block
    if (t == 1023) bsum[blockIdx.x] = buf[1023];
    if (t < 64) bcnt[t * nblk + blockIdx.x] = lh[t];
}

__global__ void scan2(int* __restrict__ bsum, int nb) {   // nb <= 64, 1 wave
    int t = threadIdx.x;
    int v = (t < nb) ? bsum[t] : 0;
    int s = v;
#pragma unroll
    for (int off = 1; off < 64; off <<= 1) {
        int u = __shfl_up(s, off, 64);
        if (t >= off) s += u;
    }
    if (t < nb) bsum[t] = s - v;             // exclusive
}

__global__ __launch_bounds__(256) void scan3(const int* __restrict__ pre,
                                             const int* __restrict__ bsum,
                                             int* __restrict__ rowptr, int n) {
    int i = blockIdx.x * 256 + threadIdx.x;
    if (i < n) rowptr[i] = pre[i] + bsum[i >> 10];
}

__global__ void fill_csr(const int* __restrict__ ei, int E, int Etot,
                         const int* __restrict__ rowptr, int* __restrict__ cursor,
                         int* __restrict__ csrc) {
    int e = blockIdx.x * blockDim.x + threadIdx.x;
    if (e >= Etot) return;
    int s, d;
    if (e < E) { s = ei[e]; d = ei[E + e]; }
    else       { s = e - E; d = s; }
    int pos = rowptr[d] + atomicAdd(&cursor[d], 1);
    csrc[pos] = s;
}

// generic single-block exclusive scan (looping 1024-chunks)
__global__ __launch_bounds__(1024) void scan_flat(int* __restrict__ data, int n) {
    __shared__ int buf[1024];
    int t = threadIdx.x;
    int carry = 0;
    for (int base = 0; base < n; base += 1024) {
        int i = base + t;
        int v = (i < n) ? data[i] : 0;
        buf[t] = v;
        __syncthreads();
#pragma unroll
        for (int off = 1; off < 1024; off <<= 1) {
            int xv = (t >= off) ? buf[t - off] : 0;
            __syncthreads();
            buf[t] += xv;
            __syncthreads();
        }
        if (i < n) data[i] = carry + buf[t] - v;
        carry += buf[1023];
        __syncthreads();
    }
}

// scatter pass (1024-thread blocks, partition matches scan1h)
__global__ __launch_bounds__(1024) void dscatter2(const int* __restrict__ deg,
                                                  const int* __restrict__ bcnt,
                                                  int* __restrict__ order,
                                                  int n, int nblk) {
    __shared__ int lh[64];
    int t = threadIdx.x;
    if (t < 64) lh[t] = 0;
    __syncthreads();
    int i = blockIdx.x * 1024 + t;
    int key = 0, rank = 0;
    if (i < n) {
        key = 64 - min(deg[i], 64);
        rank = atomicAdd(&lh[key], 1);
    }
    __syncthreads();
    if (t < 64) lh[t] = bcnt[t * nblk + blockIdx.x];   // global base per bin
    __syncthreads();
    if (i < n) order[lh[key] + rank] = i;
}

template <int CPL, typename OutT>
__device__ __forceinline__ void store_out(OutT* p, const float* v) {
    if constexpr (sizeof(OutT) == 2) {
        __hip_bfloat16 h[CPL];
#pragma unroll
        for (int j = 0; j < CPL; ++j) h[j] = __float2bfloat16(v[j]);
        if constexpr (CPL == 4) *(uint2*)p = *(const uint2*)h;
        else                    *(unsigned*)p = *(const unsigned*)h;
    } else {
        if constexpr (CPL == 4) *(float4*)p = *(const float4*)v;
        else                    *(float2*)p = *(const float2*)v;
    }
}

// sum over each 16-lane row via DPP row_ror rotate-accumulate: 4 x v_add_dpp.
__device__ __forceinline__ float row_sum16(float x) {
    int v;
    v = __builtin_amdgcn_update_dpp(0, __float_as_int(x), 0x121, 0xF, 0xF, true);
    x += __int_as_float(v);
    v = __builtin_amdgcn_update_dpp(0, __float_as_int(x), 0x122, 0xF, 0xF, true);
    x += __int_as_float(v);
    v = __builtin_amdgcn_update_dpp(0, __float_as_int(x), 0x124, 0xF, 0xF, true);
    x += __int_as_float(v);
    v = __builtin_amdgcn_update_dpp(0, __float_as_int(x), 0x128, 0xF, 0xF, true);
    x += __int_as_float(v);
    return x;
}

// ---- fused GATv2 attention + aggregate: NW nodes per wave (degree-sorted),
// defer-max softmax in log2 domain, DPP row-sum reduce, 4-edge aligned batches
// (padded CSR), packed fma, max-form leaky (exact), scalar row base (NW=1),
// full/tail batch split (tail masking only in the final batch).
// XLR[N][S]: XL = cols 0..C-1, XR = cols C..2C-1.  NO GLOBAL ATOMICS.
template <int C, int H, int S, int NW, typename OutT>
__global__ __launch_bounds__(256) void gat_agg(
        const __hip_bfloat16* __restrict__ XLR,
        const int* __restrict__ rowptr, const int* __restrict__ deg,
        const int4* __restrict__ csrc4, const int* __restrict__ order,
        const float* __restrict__ att, const float* __restrict__ bias,
        OutT* __restrict__ OUT, int N) {
    constexpr int LPN = 64 / NW;         // lanes per node (64 or 32)
    constexpr int CPL = C / LPN;         // channels per lane (4 in all uses)
    constexpr int NP  = CPL / 2;         // float2 pairs per lane
    constexpr int LPH = LPN / H;         // lanes per head (16 or 32)
    static_assert(LPH == 16 || LPH == 32, "reduce path");
    const int wv   = (blockIdx.x * blockDim.x + threadIdx.x) >> 6;
    const int lane = threadIdx.x & 63;
    const int sub  = (NW == 2) ? (lane >> 5) : 0;
    const int ln   = lane & (LPN - 1);
    const int nid  = wv * NW + sub;
    if (nid >= N) return;
    // node/e0/dg are wave-uniform for NW==1: force to SGPRs.
    int node = order[nid];
    if constexpr (NW == 1) node = __builtin_amdgcn_readfirstlane(node);
    const unsigned ch0 = ln * CPL;

    // att pre-scaled by log2e; leaky via max(v, 0.2v) (exact)
    f32x2 xr2[NP], ca[NP];
    const f32x2 k02 = {NEG_SLOPE, NEG_SLOPE};
    {
        const __hip_bfloat16* xr = XLR + (size_t)node * S + C + ch0;
#pragma unroll
        for (int p = 0; p < NP; ++p) {
            unsigned u = ((const unsigned*)xr)[p];
            xr2[p] = f32x2{__uint_as_float(u << 16),
                           __uint_as_float(u & 0xffff0000u)};
            ca[p] = f32x2{att[ch0 + 2 * p] * LOG2E,
                          att[ch0 + 2 * p + 1] * LOG2E};
        }
    }

    int e0 = rowptr[node];
    int dg = deg[node];                  // true degree (>=1, self-loop)
    if constexpr (NW == 1) {
        e0 = __builtin_amdgcn_readfirstlane(e0);
        dg = __builtin_amdgcn_readfirstlane(dg);
    }
    const int e1  = e0 + dg;
    const int nb4 = (dg + 3) >> 2;       // padded batches
    const int4* cb = csrc4 + (e0 >> 2);  // e0 is a multiple of 4

    float m = -INFINITY, sumw = 0.f;
    f32x2 acc2[NP] = {};

    auto ldrow4 = [&](f32x2 (*dst)[NP], int4 idx) {
        int ids[4] = {idx.x, idx.y, idx.z, idx.w};
#pragma unroll
        for (int i = 0; i < 4; ++i) {
            const __hip_bfloat16* rp;
            if constexpr (NW == 1) {     // wave-uniform row -> scalar base
                int sidx = __builtin_amdgcn_readfirstlane(ids[i]);
                rp = XLR + (size_t)sidx * S;
            } else {                     // per-half-wave rows -> vector addr
                rp = XLR + (size_t)(unsigned)ids[i] * S;
            }
            uint2 u = *(const uint2*)(rp + ch0);
            dst[i][0] = f32x2{__uint_as_float(u.x << 16),
                              __uint_as_float(u.x & 0xffff0000u)};
            dst[i][1] = f32x2{__uint_as_float(u.y << 16),
                              __uint_as_float(u.y & 0xffff0000u)};
        }
    };

    // FULL = batch known fully valid (skip tail masking)
    auto process = [&](f32x2 (*xl)[NP], int k, bool full) {
        float l[4];
#pragma unroll
        for (int i = 0; i < 4; ++i) {
            f32x2 s = {0.f, 0.f};
#pragma unroll
            for (int p = 0; p < NP; ++p) {
                f32x2 v  = xl[i][p] + xr2[p];                  // v_pk_add_f32
                f32x2 lv = __builtin_elementwise_max(v, v * k02); // pk_mul+pk_max
                s = __builtin_elementwise_fma(ca[p], lv, s);   // v_pk_fma_f32
            }
            float partial = row_sum16(s.x + s.y);
            if constexpr (LPH == 32)                           // cross-row step
                partial += __int_as_float(__builtin_amdgcn_ds_swizzle(
                    __float_as_int(partial), 0x401F));         // xor 16
            l[i] = partial;
        }
        if (!full) {                                           // tail batch only
#pragma unroll
            for (int i = 0; i < 4; ++i)
                if (k + i >= e1) l[i] = -INFINITY;
        }
        float lmax = fmaxf(fmaxf(l[0], l[1]), fmaxf(l[2], l[3]));
        // defer-max (log2 domain): rescale only on >8*log2e growth
        if (lmax > m + 11.5416f) {
            float rs = __builtin_amdgcn_exp2f(m - lmax);
            f32x2 rs2 = {rs, rs};
            sumw *= rs;
#pragma unroll
            for (int p = 0; p < NP; ++p) acc2[p] *= rs2;
            m = lmax;
        }
        float w0 = __builtin_amdgcn_exp2f(l[0] - m);
        float w1 = __builtin_amdgcn_exp2f(l[1] - m);
        float w2 = __builtin_amdgcn_exp2f(l[2] - m);
        float w3 = __builtin_amdgcn_exp2f(l[3] - m);
        sumw += (w0 + w1) + (w2 + w3);
        f32x2 v0 = {w0, w0}, v1 = {w1, w1}, v2 = {w2, w2}, v3 = {w3, w3};
#pragma unroll
        for (int p = 0; p < NP; ++p) {
            f32x2 a = acc2[p];
            a = __builtin_elementwise_fma(v0, xl[0][p], a);
            a = __builtin_elementwise_fma(v1, xl[1][p], a);
            a = __builtin_elementwise_fma(v2, xl[2][p], a);
            a = __builtin_elementwise_fma(v3, xl[3][p], a);
            acc2[p] = a;
        }
    };

    f32x2 bufA[4][NP], bufB[4][NP];
    int4 idxA = cb[0], idxB;
    ldrow4(bufA, idxA);
    if (nb4 > 1) idxB = cb[1];

    const bool aligned = (dg & 3) == 0;  // last batch full if degree % 4 == 0
    int bi = 0, k = e0;
    while (true) {
        bool last = (bi == nb4 - 1);
        if (!last) ldrow4(bufB, idxB);
        if (bi + 2 < nb4) idxA = cb[bi + 2];
        process(bufA, k, !last || aligned);
        ++bi; k += 4;
        if (bi >= nb4) break;
        last = (bi == nb4 - 1);
        if (!last) ldrow4(bufA, idxA);
        if (bi + 2 < nb4) idxB = cb[bi + 2];
        process(bufB, k, !last || aligned);
        ++bi; k += 4;
        if (bi >= nb4) break;
    }

    float inv = 1.f / sumw;
    float o[CPL];
#pragma unroll
    for (int p = 0; p < NP; ++p) {
        o[2 * p]     = fmaf(acc2[p].x, inv, bias[ch0 + 2 * p]);
        o[2 * p + 1] = fmaf(acc2[p].y, inv, bias[ch0 + 2 * p + 1]);
    }
    store_out<CPL>(OUT + (size_t)node * C + ch0, o);
}

// -------- batchnorm stats: per-block partials, LDS-combined, NO atomics ------
__global__ __launch_bounds__(256) void bn_stats(const __hip_bfloat16* __restrict__ Hm,
        float* __restrict__ ps, float* __restrict__ pq, int N, int C) {
    __shared__ float ls[512], lq[512];
    int t = threadIdx.x;                 // C == 256
    int cp = t & 127, half = t >> 7;
    int ch = cp << 1;
    int r = blockIdx.x * 128 + half;
    int rend = min(N, blockIdx.x * 128 + 128);
    float s0 = 0.f, q0 = 0.f, s1 = 0.f, q1 = 0.f;
    for (; r < rend; r += 2) {
        unsigned u = *(const unsigned*)(Hm + (size_t)r * C + ch);
        float v0 = __uint_as_float(u << 16);
        float v1 = __uint_as_float(u & 0xffff0000u);
        s0 += v0; q0 = fmaf(v0, v0, q0);
        s1 += v1; q1 = fmaf(v1, v1, q1);
    }
    ls[half * 256 + ch] = s0;  ls[half * 256 + ch + 1] = s1;
    lq[half * 256 + ch] = q0;  lq[half * 256 + ch + 1] = q1;
    __syncthreads();
    ps[(size_t)blockIdx.x * 256 + t] = ls[t] + ls[256 + t];
    pq[(size_t)blockIdx.x * 256 + t] = lq[t] + lq[256 + t];
}

// fold partials -> mu[c], sc[c]: one block PER CHANNEL (parallel)
__global__ __launch_bounds__(256) void bn_reduce(const float* __restrict__ ps,
        const float* __restrict__ pq, const float* __restrict__ gamma,
        float* __restrict__ mu, float* __restrict__ sc, int nblk, float invN) {
    __shared__ float ls[256], lq[256];
    const int c = blockIdx.x;            // channel 0..255
    const int t = threadIdx.x;
    float s = 0.f, q = 0.f;
    for (int b = t; b < nblk; b += 256) {     // <=2 loads/thread, all in flight
        s += ps[(size_t)b * 256 + c];
        q += pq[(size_t)b * 256 + c];
    }
    ls[t] = s; lq[t] = q;
    __syncthreads();
#pragma unroll
    for (int off = 128; off > 0; off >>= 1) {
        if (t < off) { ls[t] += ls[t + off]; lq[t] += lq[t + off]; }
        __syncthreads();
    }
    if (t == 0) {
        float m = ls[0] * invN;
        float var = lq[0] * invN - m * m;
        mu[c] = m;
        sc[c] = gamma[c] * rsqrtf(var + BN_EPS);
    }
}

// ------------- batchnorm apply + ELU (bf16 I/O, precomputed mu/sc) ----------
__global__ __launch_bounds__(256) void bn_elu(const __hip_bfloat16* __restrict__ Hm,
        __hip_bfloat16* __restrict__ Ob,
        const float* __restrict__ mu, const float* __restrict__ sc,
        const float* __restrict__ beta, int total4, int C) {  // total4 = N*C/4
    int i4 = blockIdx.x * 256 + threadIdx.x;
    if (i4 >= total4) return;
    int ch = (i4 << 2) & (C - 1);
    uint2 u = ((const uint2*)Hm)[i4];
    unsigned uu[2] = {u.x, u.y};
    __hip_bfloat16 h[4];
#pragma unroll
    for (int w = 0; w < 2; ++w) {
#pragma unroll
        for (int j = 0; j < 2; ++j) {
            float v = (j == 0) ? __uint_as_float(uu[w] << 16)
                               : __uint_as_float(uu[w] & 0xffff0000u);
            int c = ch + 2 * w + j;
            v = (v - mu[c]) * sc[c] + beta[c];
            v = v > 0.f ? v : __builtin_amdgcn_exp2f(v * LOG2E) - 1.f;
            h[2 * w + j] = __float2bfloat16(v);
        }
    }
    ((uint2*)Ob)[i4] = *(const uint2*)h;
}

extern "C" void kernel_launch(void* const* d_in, const int* in_sizes, int n_in,
                              void* d_out, int out_size, void* d_ws, size_t ws_size,
                              hipStream_t stream) {
    const float* x    = (const float*)d_in[0];
    const int*   ei   = (const int*)d_in[1];
    const float* Wl1  = (const float*)d_in[2];
    const float* Wr1  = (const float*)d_in[3];
    const float* att1 = (const float*)d_in[4];
    const float* b1   = (const float*)d_in[5];
    const float* g1   = (const float*)d_in[6];
    const float* be1  = (const float*)d_in[7];
    const float* Wl2  = (const float*)d_in[8];
    const float* Wr2  = (const float*)d_in[9];
    const float* att2 = (const float*)d_in[10];
    const float* b2   = (const float*)d_in[11];
    const float* g2   = (const float*)d_in[12];
    const float* be2  = (const float*)d_in[13];
    const float* Wl3  = (const float*)d_in[14];
    const float* Wr3  = (const float*)d_in[15];
    const float* att3 = (const float*)d_in[16];
    const float* b3   = (const float*)d_in[17];
    float* out = (float*)d_out;

    const int IN_F = 128, HC = 256, OUT_F = 128;
    const int N = in_sizes[0] / IN_F;     // 50000
    const int E = in_sizes[1] / 2;        // 800000
    const int Etot = E + N;               // 850000
    const int EP = Etot + 3 * N;          // padded-CSR capacity bound

    // ---- workspace carve-up ----
    char* p = (char*)d_ws;
    auto alloc = [&](size_t bytes) {
        void* r = (void*)p;
        p += (bytes + 255) & ~(size_t)255;
        return r;
    };
    __hip_bfloat16* XLR  = (__hip_bfloat16*)alloc((size_t)N * 2 * HC * 2);  // [N][512]
    __hip_bfloat16* Hb   = (__hip_bfloat16*)alloc((size_t)N * HC * 2);
    __hip_bfloat16* Hbb  = (__hip_bfloat16*)alloc((size_t)N * HC * 2);
    __hip_bfloat16* xbf  = (__hip_bfloat16*)alloc((size_t)N * IN_F * 2);
    __hip_bfloat16* Wc1  = (__hip_bfloat16*)alloc((size_t)2 * HC * IN_F * 2);   // [512][128]
    __hip_bfloat16* Wc2  = (__hip_bfloat16*)alloc((size_t)2 * HC * HC * 2);     // [512][256]
    __hip_bfloat16* Wc3  = (__hip_bfloat16*)alloc((size_t)2 * OUT_F * HC * 2);  // [256][256]
    // zero-init block: deg, cursor, csrc -> ONE memset
    char* z0 = p;
    int* deg       = (int*)alloc((size_t)N * 4);
    int* cursor    = (int*)alloc((size_t)N * 4);
    int* csrc      = (int*)alloc((size_t)EP * 4 + 16);
    size_t zbytes  = (size_t)(p - z0);
    int* pre       = (int*)alloc((size_t)N * 4);
    int* bsum      = (int*)alloc(64 * 4);
    int* rowptr    = (int*)alloc((size_t)N * 4);
    int* order     = (int*)alloc((size_t)N * 4);
    int* bcnt      = (int*)alloc((size_t)64 * 64 * 4);   // [64 bins][<=64 blocks]
    const int nsb  = (N + 127) / 128;                    // bn_stats blocks (391)
    float* ps      = (float*)alloc((size_t)nsb * 256 * 4);
    float* pq      = (float*)alloc((size_t)nsb * 256 * 4);
    float* bmu     = (float*)alloc((size_t)HC * 4);
    float* bsc     = (float*)alloc((size_t)HC * 4);

    const int eb = (Etot + 255) / 256;
    const int nb = (N + 3) / 4;                          // 1 node/wave blocks
    const int nb3 = ((N + 1) / 2 + 3) / 4;               // 2 nodes/wave blocks
    const int nb256 = (N + 255) / 256;
    const int gemmRows = (N + 127) / 128;
    const int scanB = (N + 1023) / 1024;

    // ---- startup: memset FIRST (deg zero), then fused conv + count_deg -----
    hipMemsetAsync(z0, 0, zbytes, stream);
    {
        int gx = N * IN_F / 4 / 256 + 1;
        if (eb > gx) gx = eb;
        conv_all<<<dim3(gx, 8), 256, 0, stream>>>(
            x, xbf, N * IN_F / 4, Wl1, Wr1, Wl2, Wr2, Wl3, Wr3,
            Wc1, Wc2, Wc3, IN_F, HC, OUT_F, ei, E, Etot, deg);
    }

    // ---- padded CSR by dst + degree-descending order (built once) ----
    scan1h<<<scanB, 1024, 0, stream>>>(deg, pre, bsum, bcnt, N, scanB);
    scan2<<<1, 64, 0, stream>>>(bsum, scanB);
    scan3<<<nb256, 256, 0, stream>>>(pre, bsum, rowptr, N);
    fill_csr<<<eb, 256, 0, stream>>>(ei, E, Etot, rowptr, cursor, csrc);
    scan_flat<<<1, 1024, 0, stream>>>(bcnt, 64 * scanB);
    dscatter2<<<scanB, 1024, 0, stream>>>(deg, bcnt, order, N, scanB);

    // ================= Layer 1 (K=128): one GEMM -> XLR[N][512] =============
    gemm_mfma<128><<<dim3(4, gemmRows), 256, 0, stream>>>(xbf, Wc1, XLR, N, 2 * HC);
    gat_agg<256, 4, 512, 1><<<nb, 256, 0, stream>>>(
        XLR, rowptr, deg, (const int4*)csrc, order, att1, b1, Hb, N);
    bn_stats<<<nsb, 256, 0, stream>>>(Hb, ps, pq, N, HC);
    bn_reduce<<<HC, 256, 0, stream>>>(ps, pq, g1, bmu, bsc, nsb, 1.f / N);
    bn_elu<<<(N * HC / 4 + 255) / 256, 256, 0, stream>>>(Hb, Hbb, bmu, bsc, be1,
                                                         N * HC / 4, HC);

    // ================= Layer 2 (K=256) ======================================
    gemm_mfma<256><<<dim3(4, gemmRows), 256, 0, stream>>>(Hbb, Wc2, XLR, N, 2 * HC);
    gat_agg<256, 4, 512, 1><<<nb, 256, 0, stream>>>(
        XLR, rowptr, deg, (const int4*)csrc, order, att2, b2, Hb, N);
    bn_stats<<<nsb, 256, 0, stream>>>(Hb, ps, pq, N, HC);
    bn_reduce<<<HC, 256, 0, stream>>>(ps, pq, g2, bmu, bsc, nsb, 1.f / N);
    bn_elu<<<(N * HC / 4 + 255) / 256, 256, 0, stream>>>(Hb, Hbb, bmu, bsc, be2,
                                                         N * HC / 4, HC);

    // ================= Layer 3 (K=256, 1 head, 128 ch, 2 nodes/wave) ========
    gemm_mfma<256><<<dim3(2, gemmRows), 256, 0, stream>>>(Hbb, Wc3, XLR, N, 2 * OUT_F);
    gat_agg<128, 1, 256, 2><<<nb3, 256, 0, stream>>>(
        XLR, rowptr, deg, (const int4*)csrc, order, att3, b3, out, N);
}

// Round 15
// 415.727 us; speedup vs baseline: 1.0173x; 1.0173x over previous
//
#include <hip/hip_runtime.h>
#include <hip/hip_bf16.h>
#include <math.h>

#define NEG_SLOPE 0.2f
#define BN_EPS 1e-5f
#define LOG2E 1.44269504f

using frag  = __attribute__((ext_vector_type(8))) short;   // 8 x bf16
using f32x4 = __attribute__((ext_vector_type(4))) float;
using f32x2 = __attribute__((ext_vector_type(2))) float;   // -> v_pk_* ops

#define GLOAD_LDS16(gp, lp) __builtin_amdgcn_global_load_lds( \
    (const __attribute__((address_space(1))) void*)(gp),      \
    (__attribute__((address_space(3))) void*)(lp), 16, 0, 0)

// ------- merged one-time conversions: y=0 -> x cast, y=1..6 -> W transposes ---
__global__ __launch_bounds__(256) void conv_all(
        const float* __restrict__ x, __hip_bfloat16* __restrict__ xbf, int n4,
        const float* __restrict__ W1l, const float* __restrict__ W1r,
        const float* __restrict__ W2l, const float* __restrict__ W2r,
        const float* __restrict__ W3l, const float* __restrict__ W3r,
        __hip_bfloat16* __restrict__ Wc1, __hip_bfloat16* __restrict__ Wc2,
        __hip_bfloat16* __restrict__ Wc3, int INF, int HC, int OUTF) {
    if (blockIdx.y == 0) {
        int i = blockIdx.x * 256 + threadIdx.x;
        if (i >= n4) return;
        float4 v = *(const float4*)(x + (size_t)i * 4);
        __hip_bfloat16 h[4] = {__float2bfloat16(v.x), __float2bfloat16(v.y),
                               __float2bfloat16(v.z), __float2bfloat16(v.w)};
        *(uint2*)(xbf + (size_t)i * 4) = *(const uint2*)h;
        return;
    }
    const float* W; __hip_bfloat16* Wt; int K, Nn;
    switch (blockIdx.y) {
        case 1:  W = W1l; Wt = Wc1;              K = INF; Nn = HC;   break;
        case 2:  W = W1r; Wt = Wc1 + HC * INF;   K = INF; Nn = HC;   break;
        case 3:  W = W2l; Wt = Wc2;              K = HC;  Nn = HC;   break;
        case 4:  W = W2r; Wt = Wc2 + HC * HC;    K = HC;  Nn = HC;   break;
        case 5:  W = W3l; Wt = Wc3;              K = HC;  Nn = OUTF; break;
        default: W = W3r; Wt = Wc3 + OUTF * HC;  K = HC;  Nn = OUTF; break;
    }
    int i = blockIdx.x * 256 + threadIdx.x;
    if (i >= K * Nn) return;
    int k = i / Nn, n = i - k * Nn;
    Wt[n * K + k] = __float2bfloat16(W[i]);
}

// --------- bf16 MFMA GEMM: C[M,NC](bf16) = A[M,K](bf16) @ Bt[NC,K]^T ---------
// 128x128 tile, BK=32, 256 threads (4 waves 2x2), dbuf LDS via global_load_lds,
// XOR swizzle on both sides; epilogue staged through LDS for coalesced stores.
template <int K>
__global__ __launch_bounds__(256) void gemm_mfma(
        const __hip_bfloat16* __restrict__ A,
        const __hip_bfloat16* __restrict__ Bt,
        __hip_bfloat16* __restrict__ C,
        int M, int NC) {
    constexpr int KS = K / 32;
    // overlay: staging (2*[128][32] x2 = 32 KB) then C-tile [128][144] (36.9 KB)
    __shared__ __align__(16) __hip_bfloat16 smem[128 * 144];
    auto Alds = reinterpret_cast<__hip_bfloat16(*)[128][32]>(smem);          // [2][128][32]
    auto Blds = reinterpret_cast<__hip_bfloat16(*)[128][32]>(smem + 8192);   // [2][128][32]
    const int tid  = threadIdx.x;
    const int w    = tid >> 6;
    const int lane = tid & 63;
    const int wr   = w >> 1, wc = w & 1;
    const int bm = blockIdx.y * 128, bn = blockIdx.x * 128;

    auto stage = [&](int t, int b) {
        const int k0 = t * 32;
#pragma unroll
        for (int i = 0; i < 2; ++i) {
            int ld    = (w << 1) | i;          // 0..7
            int rrel0 = ld << 4;               // 16-row group
            int rrel  = rrel0 + (lane >> 2);
            int slot  = lane & 3;
            int cg    = ((slot ^ ((rrel >> 1) & 3)) << 3);  // pre-swizzled col grp
            int arow  = bm + rrel; arow = arow < M ? arow : M - 1;
            GLOAD_LDS16(A  + (size_t)arow * K + k0 + cg, &Alds[b][rrel0][0]);
            int brow  = bn + rrel;             // NC multiple of 128 -> in range
            GLOAD_LDS16(Bt + (size_t)brow * K + k0 + cg, &Blds[b][rrel0][0]);
        }
    };

    f32x4 acc[4][4] = {};
    stage(0, 0);
    __syncthreads();                           // drains vmcnt before reads

    const int fr = lane & 15, fq = lane >> 4;
    for (int t = 0; t < KS; ++t) {
        const int b = t & 1;
        if (t + 1 < KS) stage(t + 1, b ^ 1);
        frag af[4], bf[4];
#pragma unroll
        for (int mf = 0; mf < 4; ++mf) {
            int arel = (wr << 6) + (mf << 4) + fr;
            int p = fq ^ ((arel >> 1) & 3);
            af[mf] = *(const frag*)&Alds[b][arel][p << 3];
        }
#pragma unroll
        for (int nf = 0; nf < 4; ++nf) {
            int nrel = (wc << 6) + (nf << 4) + fr;
            int p = fq ^ ((nrel >> 1) & 3);
            bf[nf] = *(const frag*)&Blds[b][nrel][p << 3];
        }
#pragma unroll
        for (int mf = 0; mf < 4; ++mf)
#pragma unroll
            for (int nf = 0; nf < 4; ++nf)
                acc[mf][nf] = __builtin_amdgcn_mfma_f32_16x16x32_bf16(
                    af[mf], bf[nf], acc[mf][nf], 0, 0, 0);
        __syncthreads();                       // also drains next-stage vmcnt
    }

    // ---- epilogue: fragments -> LDS -> coalesced 16B/lane stores ----
    // C/D layout: col = lane&15, row = (lane>>4)*4 + reg   [m89-verified]
    auto Cs = reinterpret_cast<__hip_bfloat16(*)[144]>(smem);  // stride 288B
#pragma unroll
    for (int mf = 0; mf < 4; ++mf)
#pragma unroll
        for (int nf = 0; nf < 4; ++nf)
#pragma unroll
            for (int r = 0; r < 4; ++r)
                Cs[(wr << 6) + (mf << 4) + (fq << 2) + r]
                  [(wc << 6) + (nf << 4) + fr] = __float2bfloat16(acc[mf][nf][r]);
    __syncthreads();
    const int rrow  = tid >> 4;                // 0..15
    const int chunk = tid & 15;                // 16B chunk within row
#pragma unroll
    for (int pass = 0; pass < 8; ++pass) {
        int lr = pass * 16 + rrow;
        int grow = bm + lr;
        if (grow < M) {
            uint4 v = *(const uint4*)&Cs[lr][chunk << 3];
            *(uint4*)(C + (size_t)grow * NC + bn + (chunk << 3)) = v;
        }
    }
}

// ---------------- CSR build (rows padded to multiples of 4) ----------------
__global__ void count_deg(const int* __restrict__ ei, int E, int Etot,
                          int* __restrict__ deg) {
    int e = blockIdx.x * blockDim.x + threadIdx.x;
    if (e >= Etot) return;
    int d = (e < E) ? ei[E + e] : (e - E);   // self-loop for e >= E
    atomicAdd(&deg[d], 1);
}

// scan of PADDED degrees + per-block degree histogram (fused)
__global__ __launch_bounds__(1024) void scan1h(const int* __restrict__ deg,
                                               int* __restrict__ pre,
                                               int* __restrict__ bsum,
                                               int* __restrict__ bcnt,
                                               int n, int nblk) {
    __shared__ int buf[1024];
    __shared__ int lh[64];
    int t = threadIdx.x;
    if (t < 64) lh[t] = 0;
    __syncthreads();
    int i = blockIdx.x * 1024 + t;
    int d = (i < n) ? deg[i] : 0;
    if (i < n) atomicAdd(&lh[64 - min(d, 64)], 1);
    int v = (i < n) ? ((d + 3) & ~3) : 0;    // padded degree
    buf[t] = v;
    __syncthreads();
#pragma unroll
    for (int off = 1; off < 1024; off <<= 1) {
        int xv = (t >= off) ? buf[t - off] : 0;
        __syncthreads();
        buf[t] += xv;
        __syncthreads();
    }
    if (i < n) pre[i] = buf[t] - v;          // exclusive within block
    if (t == 1023) bsum[blockIdx.x] = buf[1023];
    if (t < 64) bcnt[t * nblk + blockIdx.x] = lh[t];
}

__global__ void scan2(int* __restrict__ bsum, int nb) {   // nb <= 64, 1 wave
    int t = threadIdx.x;
    int v = (t < nb) ? bsum[t] : 0;
    int s = v;
#pragma unroll
    for (int off = 1; off < 64; off <<= 1) {
        int u = __shfl_up(s, off, 64);
        if (t >= off) s += u;
    }
    if (t < nb) bsum[t] = s - v;             // exclusive
}

__global__ __launch_bounds__(256) void scan3(const int* __restrict__ pre,
                                             const int* __restrict__ bsum,
                                             int* __restrict__ rowptr, int n) {
    int i = blockIdx.x * 256 + threadIdx.x;
    if (i < n) rowptr[i] = pre[i] + bsum[i >> 10];
}

__global__ void fill_csr(const int* __restrict__ ei, int E, int Etot,
                         const int* __restrict__ rowptr, int* __restrict__ cursor,
                         int* __restrict__ csrc) {
    int e = blockIdx.x * blockDim.x + threadIdx.x;
    if (e >= Etot) return;
    int s, d;
    if (e < E) { s = ei[e]; d = ei[E + e]; }
    else       { s = e - E; d = s; }
    int pos = rowptr[d] + atomicAdd(&cursor[d], 1);
    csrc[pos] = s;
}

// generic single-block exclusive scan (looping 1024-chunks)
__global__ __launch_bounds__(1024) void scan_flat(int* __restrict__ data, int n) {
    __shared__ int buf[1024];
    int t = threadIdx.x;
    int carry = 0;
    for (int base = 0; base < n; base += 1024) {
        int i = base + t;
        int v = (i < n) ? data[i] : 0;
        buf[t] = v;
        __syncthreads();
#pragma unroll
        for (int off = 1; off < 1024; off <<= 1) {
            int xv = (t >= off) ? buf[t - off] : 0;
            __syncthreads();
            buf[t] += xv;
            __syncthreads();
        }
        if (i < n) data[i] = carry + buf[t] - v;
        carry += buf[1023];
        __syncthreads();
    }
}

// scatter pass (1024-thread blocks, partition matches scan1h)
__global__ __launch_bounds__(1024) void dscatter2(const int* __restrict__ deg,
                                                  const int* __restrict__ bcnt,
                                                  int* __restrict__ order,
                                                  int n, int nblk) {
    __shared__ int lh[64];
    int t = threadIdx.x;
    if (t < 64) lh[t] = 0;
    __syncthreads();
    int i = blockIdx.x * 1024 + t;
    int key = 0, rank = 0;
    if (i < n) {
        key = 64 - min(deg[i], 64);
        rank = atomicAdd(&lh[key], 1);
    }
    __syncthreads();
    if (t < 64) lh[t] = bcnt[t * nblk + blockIdx.x];   // global base per bin
    __syncthreads();
    if (i < n) order[lh[key] + rank] = i;
}

template <int CPL, typename OutT>
__device__ __forceinline__ void store_out(OutT* p, const float* v) {
    if constexpr (sizeof(OutT) == 2) {
        __hip_bfloat16 h[CPL];
#pragma unroll
        for (int j = 0; j < CPL; ++j) h[j] = __float2bfloat16(v[j]);
        if constexpr (CPL == 4) *(uint2*)p = *(const uint2*)h;
        else                    *(unsigned*)p = *(const unsigned*)h;
    } else {
        if constexpr (CPL == 4) *(float4*)p = *(const float4*)v;
        else                    *(float2*)p = *(const float2*)v;
    }
}

// sum over each 16-lane row via DPP row_ror rotate-accumulate: 4 x v_add_dpp.
__device__ __forceinline__ float row_sum16(float x) {
    int v;
    v = __builtin_amdgcn_update_dpp(0, __float_as_int(x), 0x121, 0xF, 0xF, true);
    x += __int_as_float(v);
    v = __builtin_amdgcn_update_dpp(0, __float_as_int(x), 0x122, 0xF, 0xF, true);
    x += __int_as_float(v);
    v = __builtin_amdgcn_update_dpp(0, __float_as_int(x), 0x124, 0xF, 0xF, true);
    x += __int_as_float(v);
    v = __builtin_amdgcn_update_dpp(0, __float_as_int(x), 0x128, 0xF, 0xF, true);
    x += __int_as_float(v);
    return x;
}

// ---- fused GATv2 attention + aggregate: NW nodes per wave (degree-sorted),
// defer-max softmax in log2 domain, DPP row-sum reduce, 4-edge aligned batches
// (padded CSR), packed fma, max-form leaky (exact), scalar row base (NW=1).
// XLR[N][S]: XL = cols 0..C-1, XR = cols C..2C-1.  NO GLOBAL ATOMICS.
template <int C, int H, int S, int NW, typename OutT>
__global__ __launch_bounds__(256) void gat_agg(
        const __hip_bfloat16* __restrict__ XLR,
        const int* __restrict__ rowptr, const int* __restrict__ deg,
        const int4* __restrict__ csrc4, const int* __restrict__ order,
        const float* __restrict__ att, const float* __restrict__ bias,
        OutT* __restrict__ OUT, int N) {
    constexpr int LPN = 64 / NW;         // lanes per node (64 or 32)
    constexpr int CPL = C / LPN;         // channels per lane (4 in all uses)
    constexpr int NP  = CPL / 2;         // float2 pairs per lane
    constexpr int LPH = LPN / H;         // lanes per head (16 or 32)
    static_assert(LPH == 16 || LPH == 32, "reduce path");
    const int wv   = (blockIdx.x * blockDim.x + threadIdx.x) >> 6;
    const int lane = threadIdx.x & 63;
    const int sub  = (NW == 2) ? (lane >> 5) : 0;
    const int ln   = lane & (LPN - 1);
    const int nid  = wv * NW + sub;
    if (nid >= N) return;
    // node/e0/dg are wave-uniform for NW==1: force to SGPRs.
    int node = order[nid];
    if constexpr (NW == 1) node = __builtin_amdgcn_readfirstlane(node);
    const unsigned ch0 = ln * CPL;

    // att pre-scaled by log2e; leaky via max(v, 0.2v) (exact)
    f32x2 xr2[NP], ca[NP];
    const f32x2 k02 = {NEG_SLOPE, NEG_SLOPE};
    {
        const __hip_bfloat16* xr = XLR + (size_t)node * S + C + ch0;
#pragma unroll
        for (int p = 0; p < NP; ++p) {
            unsigned u = ((const unsigned*)xr)[p];
            xr2[p] = f32x2{__uint_as_float(u << 16),
                           __uint_as_float(u & 0xffff0000u)};
            ca[p] = f32x2{att[ch0 + 2 * p] * LOG2E,
                          att[ch0 + 2 * p + 1] * LOG2E};
        }
    }

    int e0 = rowptr[node];
    int dg = deg[node];                  // true degree (>=1, self-loop)
    if constexpr (NW == 1) {
        e0 = __builtin_amdgcn_readfirstlane(e0);
        dg = __builtin_amdgcn_readfirstlane(dg);
    }
    const int e1  = e0 + dg;
    const int nb4 = (dg + 3) >> 2;       // padded batches
    const int4* cb = csrc4 + (e0 >> 2);  // e0 is a multiple of 4

    float m = -INFINITY, sumw = 0.f;
    f32x2 acc2[NP] = {};

    auto ldrow4 = [&](f32x2 (*dst)[NP], int4 idx) {
        int ids[4] = {idx.x, idx.y, idx.z, idx.w};
#pragma unroll
        for (int i = 0; i < 4; ++i) {
            const __hip_bfloat16* rp;
            if constexpr (NW == 1) {     // wave-uniform row -> scalar base
                int sidx = __builtin_amdgcn_readfirstlane(ids[i]);
                rp = XLR + (size_t)sidx * S;
            } else {                     // per-half-wave rows -> vector addr
                rp = XLR + (size_t)(unsigned)ids[i] * S;
            }
            uint2 u = *(const uint2*)(rp + ch0);
            dst[i][0] = f32x2{__uint_as_float(u.x << 16),
                              __uint_as_float(u.x & 0xffff0000u)};
            dst[i][1] = f32x2{__uint_as_float(u.y << 16),
                              __uint_as_float(u.y & 0xffff0000u)};
        }
    };

    auto process = [&](f32x2 (*xl)[NP], int k) {
        float l[4];
#pragma unroll
        for (int i = 0; i < 4; ++i) {
            f32x2 s = {0.f, 0.f};
#pragma unroll
            for (int p = 0; p < NP; ++p) {
                f32x2 v  = xl[i][p] + xr2[p];                  // v_pk_add_f32
                f32x2 lv = __builtin_elementwise_max(v, v * k02); // pk_mul+pk_max
                s = __builtin_elementwise_fma(ca[p], lv, s);   // v_pk_fma_f32
            }
            float partial = row_sum16(s.x + s.y);
            if constexpr (LPH == 32)                           // cross-row step
                partial += __int_as_float(__builtin_amdgcn_ds_swizzle(
                    __float_as_int(partial), 0x401F));         // xor 16
            l[i] = (k + i < e1) ? partial : -INFINITY;         // branchless tail
        }
        float lmax = fmaxf(fmaxf(l[0], l[1]), fmaxf(l[2], l[3]));
        // defer-max (log2 domain): rescale only on >8*log2e growth
        if (lmax > m + 11.5416f) {
            float rs = __builtin_amdgcn_exp2f(m - lmax);
            f32x2 rs2 = {rs, rs};
            sumw *= rs;
#pragma unroll
            for (int p = 0; p < NP; ++p) acc2[p] *= rs2;
            m = lmax;
        }
        float w0 = __builtin_amdgcn_exp2f(l[0] - m);
        float w1 = __builtin_amdgcn_exp2f(l[1] - m);
        float w2 = __builtin_amdgcn_exp2f(l[2] - m);
        float w3 = __builtin_amdgcn_exp2f(l[3] - m);
        sumw += (w0 + w1) + (w2 + w3);
        f32x2 v0 = {w0, w0}, v1 = {w1, w1}, v2 = {w2, w2}, v3 = {w3, w3};
#pragma unroll
        for (int p = 0; p < NP; ++p) {
            f32x2 a = acc2[p];
            a = __builtin_elementwise_fma(v0, xl[0][p], a);
            a = __builtin_elementwise_fma(v1, xl[1][p], a);
            a = __builtin_elementwise_fma(v2, xl[2][p], a);
            a = __builtin_elementwise_fma(v3, xl[3][p], a);
            acc2[p] = a;
        }
    };

    f32x2 bufA[4][NP], bufB[4][NP];
    int4 idxA = cb[0], idxB;
    ldrow4(bufA, idxA);
    if (nb4 > 1) idxB = cb[1];

    int bi = 0, k = e0;
    while (true) {
        if (bi + 1 < nb4) ldrow4(bufB, idxB);
        if (bi + 2 < nb4) idxA = cb[bi + 2];
        process(bufA, k);
        ++bi; k += 4;
        if (bi >= nb4) break;
        if (bi + 1 < nb4) ldrow4(bufA, idxA);
        if (bi + 2 < nb4) idxB = cb[bi + 2];
        process(bufB, k);
        ++bi; k += 4;
        if (bi >= nb4) break;
    }

    float inv = 1.f / sumw;
    float o[CPL];
#pragma unroll
    for (int p = 0; p < NP; ++p) {
        o[2 * p]     = fmaf(acc2[p].x, inv, bias[ch0 + 2 * p]);
        o[2 * p + 1] = fmaf(acc2[p].y, inv, bias[ch0 + 2 * p + 1]);
    }
    store_out<CPL>(OUT + (size_t)node * C + ch0, o);
}

// -------- batchnorm stats: per-block partials, LDS-combined, NO atomics ------
__global__ __launch_bounds__(256) void bn_stats(const __hip_bfloat16* __restrict__ Hm,
        float* __restrict__ ps, float* __restrict__ pq, int N, int C) {
    __shared__ float ls[512], lq[512];
    int t = threadIdx.x;                 // C == 256
    int cp = t & 127, half = t >> 7;
    int ch = cp << 1;
    int r = blockIdx.x * 128 + half;
    int rend = min(N, blockIdx.x * 128 + 128);
    float s0 = 0.f, q0 = 0.f, s1 = 0.f, q1 = 0.f;
    for (; r < rend; r += 2) {
        unsigned u = *(const unsigned*)(Hm + (size_t)r * C + ch);
        float v0 = __uint_as_float(u << 16);
        float v1 = __uint_as_float(u & 0xffff0000u);
        s0 += v0; q0 = fmaf(v0, v0, q0);
        s1 += v1; q1 = fmaf(v1, v1, q1);
    }
    ls[half * 256 + ch] = s0;  ls[half * 256 + ch + 1] = s1;
    lq[half * 256 + ch] = q0;  lq[half * 256 + ch + 1] = q1;
    __syncthreads();
    ps[(size_t)blockIdx.x * 256 + t] = ls[t] + ls[256 + t];
    pq[(size_t)blockIdx.x * 256 + t] = lq[t] + lq[256 + t];
}

// fold partials -> mu[c], sc[c]: one block PER CHANNEL (parallel)
__global__ __launch_bounds__(256) void bn_reduce(const float* __restrict__ ps,
        const float* __restrict__ pq, const float* __restrict__ gamma,
        float* __restrict__ mu, float* __restrict__ sc, int nblk, float invN) {
    __shared__ float ls[256], lq[256];
    const int c = blockIdx.x;            // channel 0..255
    const int t = threadIdx.x;
    float s = 0.f, q = 0.f;
    for (int b = t; b < nblk; b += 256) {     // <=2 loads/thread, all in flight
        s += ps[(size_t)b * 256 + c];
        q += pq[(size_t)b * 256 + c];
    }
    ls[t] = s; lq[t] = q;
    __syncthreads();
#pragma unroll
    for (int off = 128; off > 0; off >>= 1) {
        if (t < off) { ls[t] += ls[t + off]; lq[t] += lq[t + off]; }
        __syncthreads();
    }
    if (t == 0) {
        float m = ls[0] * invN;
        float var = lq[0] * invN - m * m;
        mu[c] = m;
        sc[c] = gamma[c] * rsqrtf(var + BN_EPS);
    }
}

// ------------- batchnorm apply + ELU (bf16 I/O, precomputed mu/sc) ----------
__global__ __launch_bounds__(256) void bn_elu(const __hip_bfloat16* __restrict__ Hm,
        __hip_bfloat16* __restrict__ Ob,
        const float* __restrict__ mu, const float* __restrict__ sc,
        const float* __restrict__ beta, int total4, int C) {  // total4 = N*C/4
    int i4 = blockIdx.x * 256 + threadIdx.x;
    if (i4 >= total4) return;
    int ch = (i4 << 2) & (C - 1);
    uint2 u = ((const uint2*)Hm)[i4];
    unsigned uu[2] = {u.x, u.y};
    __hip_bfloat16 h[4];
#pragma unroll
    for (int w = 0; w < 2; ++w) {
#pragma unroll
        for (int j = 0; j < 2; ++j) {
            float v = (j == 0) ? __uint_as_float(uu[w] << 16)
                               : __uint_as_float(uu[w] & 0xffff0000u);
            int c = ch + 2 * w + j;
            v = (v - mu[c]) * sc[c] + beta[c];
            v = v > 0.f ? v : __builtin_amdgcn_exp2f(v * LOG2E) - 1.f;
            h[2 * w + j] = __float2bfloat16(v);
        }
    }
    ((uint2*)Ob)[i4] = *(const uint2*)h;
}

extern "C" void kernel_launch(void* const* d_in, const int* in_sizes, int n_in,
                              void* d_out, int out_size, void* d_ws, size_t ws_size,
                              hipStream_t stream) {
    const float* x    = (const float*)d_in[0];
    const int*   ei   = (const int*)d_in[1];
    const float* Wl1  = (const float*)d_in[2];
    const float* Wr1  = (const float*)d_in[3];
    const float* att1 = (const float*)d_in[4];
    const float* b1   = (const float*)d_in[5];
    const float* g1   = (const float*)d_in[6];
    const float* be1  = (const float*)d_in[7];
    const float* Wl2  = (const float*)d_in[8];
    const float* Wr2  = (const float*)d_in[9];
    const float* att2 = (const float*)d_in[10];
    const float* b2   = (const float*)d_in[11];
    const float* g2   = (const float*)d_in[12];
    const float* be2  = (const float*)d_in[13];
    const float* Wl3  = (const float*)d_in[14];
    const float* Wr3  = (const float*)d_in[15];
    const float* att3 = (const float*)d_in[16];
    const float* b3   = (const float*)d_in[17];
    float* out = (float*)d_out;

    const int IN_F = 128, HC = 256, OUT_F = 128;
    const int N = in_sizes[0] / IN_F;     // 50000
    const int E = in_sizes[1] / 2;        // 800000
    const int Etot = E + N;               // 850000
    const int EP = Etot + 3 * N;          // padded-CSR capacity bound

    // ---- workspace carve-up ----
    char* p = (char*)d_ws;
    auto alloc = [&](size_t bytes) {
        void* r = (void*)p;
        p += (bytes + 255) & ~(size_t)255;
        return r;
    };
    __hip_bfloat16* XLR  = (__hip_bfloat16*)alloc((size_t)N * 2 * HC * 2);  // [N][512]
    __hip_bfloat16* Hb   = (__hip_bfloat16*)alloc((size_t)N * HC * 2);
    __hip_bfloat16* Hbb  = (__hip_bfloat16*)alloc((size_t)N * HC * 2);
    __hip_bfloat16* xbf  = (__hip_bfloat16*)alloc((size_t)N * IN_F * 2);
    __hip_bfloat16* Wc1  = (__hip_bfloat16*)alloc((size_t)2 * HC * IN_F * 2);   // [512][128]
    __hip_bfloat16* Wc2  = (__hip_bfloat16*)alloc((size_t)2 * HC * HC * 2);     // [512][256]
    __hip_bfloat16* Wc3  = (__hip_bfloat16*)alloc((size_t)2 * OUT_F * HC * 2);  // [256][256]
    // zero-init block: deg, cursor, csrc -> ONE memset
    char* z0 = p;
    int* deg       = (int*)alloc((size_t)N * 4);
    int* cursor    = (int*)alloc((size_t)N * 4);
    int* csrc      = (int*)alloc((size_t)EP * 4 + 16);
    size_t zbytes  = (size_t)(p - z0);
    int* pre       = (int*)alloc((size_t)N * 4);
    int* bsum      = (int*)alloc(64 * 4);
    int* rowptr    = (int*)alloc((size_t)N * 4);
    int* order     = (int*)alloc((size_t)N * 4);
    int* bcnt      = (int*)alloc((size_t)64 * 64 * 4);   // [64 bins][<=64 blocks]
    const int nsb  = (N + 127) / 128;                    // bn_stats blocks (391)
    float* ps      = (float*)alloc((size_t)nsb * 256 * 4);
    float* pq      = (float*)alloc((size_t)nsb * 256 * 4);
    float* bmu     = (float*)alloc((size_t)HC * 4);
    float* bsc     = (float*)alloc((size_t)HC * 4);

    const int eb = (Etot + 255) / 256;
    const int nb = (N + 3) / 4;                          // 1 node/wave blocks
    const int nb3 = ((N + 1) / 2 + 3) / 4;               // 2 nodes/wave blocks
    const int nb256 = (N + 255) / 256;
    const int gemmRows = (N + 127) / 128;
    const int scanB = (N + 1023) / 1024;

    // ---- one-time conversions (x cast + 6 weight transposes, one launch) ----
    conv_all<<<dim3((N * IN_F / 4 + 255) / 256, 7), 256, 0, stream>>>(
        x, xbf, N * IN_F / 4, Wl1, Wr1, Wl2, Wr2, Wl3, Wr3,
        Wc1, Wc2, Wc3, IN_F, HC, OUT_F);

    // ---- padded CSR by dst + degree-descending order (built once) ----
    hipMemsetAsync(z0, 0, zbytes, stream);
    count_deg<<<eb, 256, 0, stream>>>(ei, E, Etot, deg);
    scan1h<<<scanB, 1024, 0, stream>>>(deg, pre, bsum, bcnt, N, scanB);
    scan2<<<1, 64, 0, stream>>>(bsum, scanB);
    scan3<<<nb256, 256, 0, stream>>>(pre, bsum, rowptr, N);
    fill_csr<<<eb, 256, 0, stream>>>(ei, E, Etot, rowptr, cursor, csrc);
    scan_flat<<<1, 1024, 0, stream>>>(bcnt, 64 * scanB);
    dscatter2<<<scanB, 1024, 0, stream>>>(deg, bcnt, order, N, scanB);

    // ================= Layer 1 (K=128): one GEMM -> XLR[N][512] =============
    gemm_mfma<128><<<dim3(4, gemmRows), 256, 0, stream>>>(xbf, Wc1, XLR, N, 2 * HC);
    gat_agg<256, 4, 512, 1><<<nb, 256, 0, stream>>>(
        XLR, rowptr, deg, (const int4*)csrc, order, att1, b1, Hb, N);
    bn_stats<<<nsb, 256, 0, stream>>>(Hb, ps, pq, N, HC);
    bn_reduce<<<HC, 256, 0, stream>>>(ps, pq, g1, bmu, bsc, nsb, 1.f / N);
    bn_elu<<<(N * HC / 4 + 255) / 256, 256, 0, stream>>>(Hb, Hbb, bmu, bsc, be1,
                                                         N * HC / 4, HC);

    // ================= Layer 2 (K=256) ======================================
    gemm_mfma<256><<<dim3(4, gemmRows), 256, 0, stream>>>(Hbb, Wc2, XLR, N, 2 * HC);
    gat_agg<256, 4, 512, 1><<<nb, 256, 0, stream>>>(
        XLR, rowptr, deg, (const int4*)csrc, order, att2, b2, Hb, N);
    bn_stats<<<nsb, 256, 0, stream>>>(Hb, ps, pq, N, HC);
    bn_reduce<<<HC, 256, 0, stream>>>(ps, pq, g2, bmu, bsc, nsb, 1.f / N);
    bn_elu<<<(N * HC / 4 + 255) / 256, 256, 0, stream>>>(Hb, Hbb, bmu, bsc, be2,
                                                         N * HC / 4, HC);

    // ================= Layer 3 (K=256, 1 head, 128 ch, 2 nodes/wave) ========
    gemm_mfma<256><<<dim3(2, gemmRows), 256, 0, stream>>>(Hbb, Wc3, XLR, N, 2 * OUT_F);
    gat_agg<128, 1, 256, 2><<<nb3, 256, 0, stream>>>(
        XLR, rowptr, deg, (const int4*)csrc, order, att3, b3, out, N);
}